// Round 1
// baseline (149.479 us; speedup 1.0000x reference)
//
#include <hip/hip_runtime.h>

#define BB 64
#define NN 300   // columns (predictions)
#define TT 30    // rows (targets)
#define BIGF 1e18f

// d_out is re-poisoned 0xAA before every timed launch -> zero it ourselves.
__global__ void zero_out_kernel(float* out) {
    int tid = threadIdx.x;
    if (tid < 3) out[tid] = 0.0f;
}

// GIoU with exact reference fp32 op order (no fma contraction).
__device__ __forceinline__ float giou_xyxy(float ax0, float ay0, float ax1, float ay1, float area_a,
                                           float bx0, float by0, float bx1, float by1, float area_b) {
    float ltx = fmaxf(ax0, bx0), lty = fmaxf(ay0, by0);
    float rbx = fminf(ax1, bx1), rby = fminf(ay1, by1);
    float w = fmaxf(__fsub_rn(rbx, ltx), 0.0f);
    float h = fmaxf(__fsub_rn(rby, lty), 0.0f);
    float inter = __fmul_rn(w, h);
    float uni = __fsub_rn(__fadd_rn(area_a, area_b), inter);
    float iou = inter / uni;
    float cx0 = fminf(ax0, bx0), cy0 = fminf(ay0, by0);
    float cx1 = fmaxf(ax1, bx1), cy1 = fmaxf(ay1, by1);
    float cw = fmaxf(__fsub_rn(cx1, cx0), 0.0f);
    float ch = fmaxf(__fsub_rn(cy1, cy0), 0.0f);
    float areac = __fmul_rn(cw, ch);
    return __fsub_rn(iou, __fsub_rn(areac, uni) / areac);
}

__launch_bounds__(256, 1)
__global__ void detcrit_kernel(const float* __restrict__ pred_boxes,   // [B,N,4] xywh
                               const float* __restrict__ pred_classes, // [B,N]
                               const float* __restrict__ targets,      // [B,T,4] xywh
                               float* __restrict__ out) {              // [3]
    const int b = blockIdx.x;
    const int tid = threadIdx.x;

    __shared__ float s_pb[NN][4];   // pred xywh
    __shared__ float s_px[NN][4];   // pred xyxy
    __shared__ float s_pa[NN];      // pred area
    __shared__ float s_pc[NN];      // pred class prob
    __shared__ float s_tb[TT][4];   // tgt xywh
    __shared__ float s_tx[TT][4];   // tgt xyxy
    __shared__ float s_ta[TT];      // tgt area
    __shared__ float s_cost[TT][NN];
    __shared__ float s_u[TT];
    __shared__ float s_v[NN];
    __shared__ float s_spc[NN];
    __shared__ int   s_path[NN];
    __shared__ int   s_row4col[NN];
    __shared__ int   s_col4row[TT];
    __shared__ int   s_sorted[TT];
    __shared__ unsigned char s_SC[NN];
    __shared__ unsigned char s_SR[TT];
    __shared__ unsigned char s_lab[NN];
    __shared__ float s_redf[4];
    __shared__ int   s_redi[4];
    __shared__ float s_rc[4], s_rb[4], s_rg[4];
    __shared__ int   s_curi;
    __shared__ int   s_sink;
    __shared__ float s_minVal;

    // ---------------- Phase 0: stage inputs ----------------
    const float4* pbg = (const float4*)(pred_boxes + (size_t)b * NN * 4);
    const float4* tgg = (const float4*)(targets + (size_t)b * TT * 4);
    const float*  pcg = pred_classes + (size_t)b * NN;

    for (int n = tid; n < NN; n += 256) {
        float4 v = pbg[n];
        s_pb[n][0] = v.x; s_pb[n][1] = v.y; s_pb[n][2] = v.z; s_pb[n][3] = v.w;
        float x2 = __fadd_rn(v.x, v.z), y2 = __fadd_rn(v.y, v.w);
        s_px[n][0] = v.x; s_px[n][1] = v.y; s_px[n][2] = x2; s_px[n][3] = y2;
        s_pa[n] = __fmul_rn(__fsub_rn(x2, v.x), __fsub_rn(y2, v.y));
        s_pc[n] = pcg[n];
        s_row4col[n] = -1;
        s_v[n] = 0.0f;
        s_lab[n] = 0;
    }
    if (tid < TT) {
        float4 v = tgg[tid];
        s_tb[tid][0] = v.x; s_tb[tid][1] = v.y; s_tb[tid][2] = v.z; s_tb[tid][3] = v.w;
        float x2 = __fadd_rn(v.x, v.z), y2 = __fadd_rn(v.y, v.w);
        s_tx[tid][0] = v.x; s_tx[tid][1] = v.y; s_tx[tid][2] = x2; s_tx[tid][3] = y2;
        s_ta[tid] = __fmul_rn(__fsub_rn(x2, v.x), __fsub_rn(y2, v.y));
        s_u[tid] = 0.0f;
        s_col4row[tid] = -1;
    }
    __syncthreads();

    // ---------------- Phase 1: cost matrix [T][N] (LSA orientation) ----------------
    for (int e = tid; e < TT * NN; e += 256) {
        int t = e / NN;
        int n = e - t * NN;
        float g = giou_xyxy(s_px[n][0], s_px[n][1], s_px[n][2], s_px[n][3], s_pa[n],
                            s_tx[t][0], s_tx[t][1], s_tx[t][2], s_tx[t][3], s_ta[t]);
        float l1 = __fadd_rn(__fadd_rn(__fadd_rn(
                       fabsf(__fsub_rn(s_pb[n][0], s_tb[t][0])),
                       fabsf(__fsub_rn(s_pb[n][1], s_tb[t][1]))),
                       fabsf(__fsub_rn(s_pb[n][2], s_tb[t][2]))),
                       fabsf(__fsub_rn(s_pb[n][3], s_tb[t][3])));
        // cost = (class_part + giou_part) + bbox_part
        s_cost[t][n] = __fadd_rn(__fadd_rn(-s_pc[n], -g), l1);
    }
    __syncthreads();

    // ---------------- Phase 2: Hungarian (shortest augmenting path) ----------------
    for (int row = 0; row < TT; ++row) {
        for (int j = tid; j < NN; j += 256) { s_spc[j] = BIGF; s_SC[j] = 0; s_path[j] = 0; }
        if (tid < TT) s_SR[tid] = 0;
        if (tid == 0) { s_curi = row; s_sink = -1; s_minVal = 0.0f; }
        __syncthreads();

        int guard = 0;
        while (true) {
            int   cur_i  = s_curi;
            float minVal = s_minVal;
            if (tid == 0) s_SR[cur_i] = 1;
            float u_cur = s_u[cur_i];

            float bestv = __int_as_float(0x7f800000); // +inf
            int   bestj = 0x7fffffff;
            for (int j = tid; j < NN; j += 256) {
                float m;
                if (!s_SC[j]) {
                    float red = __fsub_rn(__fsub_rn(__fadd_rn(minVal, s_cost[cur_i][j]), u_cur), s_v[j]);
                    float sp = s_spc[j];
                    if (red < sp) { sp = red; s_spc[j] = red; s_path[j] = cur_i; }
                    m = sp;
                } else {
                    m = BIGF;
                }
                if (m < bestv || (m == bestv && j < bestj)) { bestv = m; bestj = j; }
            }
            // wave-level lexicographic (val, idx) min — matches jnp.argmin first-index
            for (int off = 32; off; off >>= 1) {
                float ov = __shfl_down(bestv, off);
                int   oj = __shfl_down(bestj, off);
                if (ov < bestv || (ov == bestv && oj < bestj)) { bestv = ov; bestj = oj; }
            }
            int wv = tid >> 6;
            if ((tid & 63) == 0) { s_redf[wv] = bestv; s_redi[wv] = bestj; }
            __syncthreads();
            if (tid == 0) {
                float bv = s_redf[0]; int bj = s_redi[0];
                for (int w2 = 1; w2 < 4; ++w2) {
                    float ov = s_redf[w2]; int oj = s_redi[w2];
                    if (ov < bv || (ov == bv && oj < bj)) { bv = ov; bj = oj; }
                }
                s_minVal = bv;
                s_SC[bj] = 1;
                int r = s_row4col[bj];
                if (r < 0) s_sink = bj; else s_curi = r;
            }
            __syncthreads();
            if (s_sink >= 0) break;
            if (++guard > NN + 2) break;  // safety: never hang the GPU
        }

        // dual updates (reference order: before augmentation)
        float minVal = s_minVal;
        if (tid < TT) {
            if (tid == row) {
                s_u[tid] = __fadd_rn(s_u[tid], minVal);
            } else if (s_SR[tid]) {
                s_u[tid] = __fadd_rn(s_u[tid], __fsub_rn(minVal, s_spc[s_col4row[tid]]));
            }
        }
        for (int j = tid; j < NN; j += 256)
            if (s_SC[j]) s_v[j] = __fsub_rn(s_v[j], __fsub_rn(minVal, s_spc[j]));
        __syncthreads();

        // augment along alternating path (scalar)
        if (tid == 0 && s_sink >= 0) {
            int j = s_sink;
            for (int it = 0; it < TT + 2; ++it) {
                int i = s_path[j];
                s_row4col[j] = i;
                int nj = s_col4row[i];
                s_col4row[i] = j;
                if (i == row) break;
                j = nj;
            }
        }
        __syncthreads();
    }

    // ---------------- Phase 3: sort matched indices (boxes_idx) ----------------
    if (tid == 0) {
        for (int i = 0; i < TT; ++i) s_sorted[i] = s_col4row[i];
        for (int i = 1; i < TT; ++i) {
            int key = s_sorted[i];
            int k = i - 1;
            while (k >= 0 && s_sorted[k] > key) { s_sorted[k + 1] = s_sorted[k]; --k; }
            s_sorted[k + 1] = key;
        }
    }
    __syncthreads();
    if (tid < TT) s_lab[s_sorted[tid]] = 1;
    __syncthreads();

    // ---------------- Phase 4: losses ----------------
    float acc_c = 0.0f, acc_b = 0.0f, acc_g = 0.0f;
    for (int n = tid; n < NN; n += 256) {
        float p = s_pc[n];
        float lp = fmaxf(logf(p), -100.0f);
        float lq = fmaxf(logf(__fsub_rn(1.0f, p)), -100.0f);
        acc_c += s_lab[n] ? -lp : -lq;
    }
    if (tid < TT) {
        int t = tid;
        int idx = s_sorted[t];
        acc_b = fabsf(s_pb[idx][0] - s_tb[t][0]) + fabsf(s_pb[idx][1] - s_tb[t][1])
              + fabsf(s_pb[idx][2] - s_tb[t][2]) + fabsf(s_pb[idx][3] - s_tb[t][3]);
        float g = giou_xyxy(s_px[idx][0], s_px[idx][1], s_px[idx][2], s_px[idx][3], s_pa[idx],
                            s_tx[t][0], s_tx[t][1], s_tx[t][2], s_tx[t][3], s_ta[t]);
        acc_g = 1.0f - g;
    }
    for (int off = 32; off; off >>= 1) {
        acc_c += __shfl_down(acc_c, off);
        acc_b += __shfl_down(acc_b, off);
        acc_g += __shfl_down(acc_g, off);
    }
    int wv = tid >> 6;
    if ((tid & 63) == 0) { s_rc[wv] = acc_c; s_rb[wv] = acc_b; s_rg[wv] = acc_g; }
    __syncthreads();
    if (tid == 0) {
        float c  = s_rc[0] + s_rc[1] + s_rc[2] + s_rc[3];
        float bx = s_rb[0] + s_rb[1] + s_rb[2] + s_rb[3];
        float g  = s_rg[0] + s_rg[1] + s_rg[2] + s_rg[3];
        atomicAdd(&out[0], c  * (1.0f / (float)(BB * NN)));
        atomicAdd(&out[1], bx * (1.0f / (float)(BB * TT)));
        atomicAdd(&out[2], g  * (1.0f / (float)(BB * TT)));
    }
}

extern "C" void kernel_launch(void* const* d_in, const int* in_sizes, int n_in,
                              void* d_out, int out_size, void* d_ws, size_t ws_size,
                              hipStream_t stream) {
    const float* pred_boxes   = (const float*)d_in[0];
    const float* pred_classes = (const float*)d_in[1];
    const float* targets      = (const float*)d_in[2];
    float* out = (float*)d_out;

    zero_out_kernel<<<1, 64, 0, stream>>>(out);
    detcrit_kernel<<<BB, 256, 0, stream>>>(pred_boxes, pred_classes, targets, out);
}